// Round 21
// baseline (284.662 us; speedup 1.0000x reference)
//
#include <hip/hip_runtime.h>
#include <hip/hip_bf16.h>
#include <math.h>

#define NTOK 8192
#define HD   1024
#define FFND 2048
#define NE   64
#define MTOT 16384   // NTOK * TOPK
#define PER_E 256    // MTOT / NE

typedef __attribute__((ext_vector_type(8))) short bh8;
typedef __attribute__((ext_vector_type(4))) float f4;
typedef __attribute__((ext_vector_type(2))) unsigned int u32x2;
typedef unsigned short u16;
typedef unsigned int   u32;

#define SB0 __builtin_amdgcn_sched_barrier(0)

__device__ __forceinline__ u16 f2bf(float f) {
  union { float f; u32 u; } x; x.f = f;
  u32 r = x.u + 0x7fffu + ((x.u >> 16) & 1u);   // round-nearest-even
  return (u16)(r >> 16);
}

__device__ __forceinline__ float bf2f(u16 b) {
  union { u32 u; float f; } x; x.u = ((u32)b) << 16; return x.f;
}

__device__ __forceinline__ u32 pk2(float lo, float hi) {
  __hip_bfloat162 h = __float22bfloat162_rn(make_float2(lo, hi));
  union { __hip_bfloat162 h; u32 u; } c; c.h = h;
  return c.u;
}

// slot -> source token map. scatter_index flat: sidx[t*2+k] = slot.
__global__ void k_build_s2t(const int* __restrict__ sidx, int* __restrict__ s2t) {
  int i = blockIdx.x * 256 + threadIdx.x;   // i in [0, MTOT)
  s2t[sidx[i]] = i >> 1;
}

// GEMM1 with FUSED gather (round-20 proven): A rows straight from inp[s2t[row]]
// (f32), reg-staged + cvt_pk -> As (XOR-preswizzled). Split counted drain.
template<int K, int N>
__global__ __launch_bounds__(512, 2)
void moe_gemm1(const float* __restrict__ inp, const int* __restrict__ s2t,
               const float* __restrict__ Bf, u16* __restrict__ actout)
{
  constexpr int BM = 256, BN = 256, BK = 64;
  constexpr int NB = N / BN;
  constexpr int NT = K / BK;
  constexpr int NF = 8;
  constexpr int ABYTES = BM * 128;            // 32 KB
  __shared__ __align__(16) char lds[ABYTES + BN * 128];  // 64 KB
  char* Bs = lds + ABYTES;

  const int d = blockIdx.y * NB + blockIdx.x;
  const int x = d & 7, j = d >> 3;
  const int e  = x * (NE / 8) + j / NB;
  const int n0 = (j % NB) * BN;
  const int row0 = e * PER_E;
  const int tid  = threadIdx.x;
  const int lane = tid & 63, wid = tid >> 6;
  const int wr   = wid >> 1, wc = wid & 1;    // 4x2 waves: 64 x 128 each

  const float* Bsrc = Bf + (size_t)e * K * N + n0;
  const int nq = (tid & 63) * 4;              // B: n-quad base
  const int kg = tid >> 6;                    // B: k-octet group

  // my 4 A-rows and their source tokens
  int arow[4]; const float* asrc[4];
  #pragma unroll
  for (int i = 0; i < 4; ++i) {
    int c = i * 512 + tid;
    arow[i] = c >> 3;
    asrc[i] = inp + (size_t)s2t[row0 + arow[i]] * K;
  }

  auto loadA = [&](f4* ar, int k0) {
    #pragma unroll
    for (int i = 0; i < 4; ++i) {
      int c = i * 512 + tid;
      int kc = c & 7, r = arow[i];
      int kswz = kc ^ (r & 7);
      const float* p = asrc[i] + k0 + kswz * 8;
      ar[i * 2]     = *(const f4*)(p);
      ar[i * 2 + 1] = *(const f4*)(p + 4);
    }
  };
  auto writeA = [&](const f4* ar) {
    #pragma unroll
    for (int i = 0; i < 4; ++i) {
      int c = i * 512 + tid;
      u32 q[4];
      q[0] = pk2(ar[i * 2][0],     ar[i * 2][1]);
      q[1] = pk2(ar[i * 2][2],     ar[i * 2][3]);
      q[2] = pk2(ar[i * 2 + 1][0], ar[i * 2 + 1][1]);
      q[3] = pk2(ar[i * 2 + 1][2], ar[i * 2 + 1][3]);
      *(uint4*)(lds + c * 16) = *(uint4*)q;   // linear dest, src pre-swizzled
    }
  };
  auto loadB = [&](f4* br4, int k0) {
    #pragma unroll
    for (int jj = 0; jj < 8; ++jj)
      br4[jj] = __builtin_nontemporal_load(
          (const f4*)(Bsrc + (size_t)(k0 + kg * 8 + jj) * N + nq));
  };
  auto writeB = [&](const f4* br4) {
    #pragma unroll
    for (int i = 0; i < 4; ++i) {
      int n = nq + i;
      u32 q[4];
      #pragma unroll
      for (int jj = 0; jj < 4; ++jj)
        q[jj] = pk2(br4[2 * jj][i], br4[2 * jj + 1][i]);
      *(uint4*)(Bs + n * 128 + ((kg * 16) ^ ((n & 7) << 4))) = *(uint4*)q;
    }
  };

  f4 acc[4][NF] = {};
  f4 breg[8], areg[8];

  // ---- prologue: tile 0 (A older, B newer) ----
  loadA(areg, 0); SB0;
  loadB(breg, 0); SB0;
  asm volatile("s_waitcnt vmcnt(8)" ::: "memory"); SB0;   // A ready
  writeA(areg);
  asm volatile("s_waitcnt vmcnt(0)" ::: "memory"); SB0;   // B ready
  writeB(breg);
  asm volatile("s_waitcnt lgkmcnt(0)" ::: "memory"); SB0;
  __builtin_amdgcn_s_barrier(); SB0;

  for (int t = 0; t < NT; ++t) {
    if (t + 1 < NT) {
      loadA(areg, (t + 1) * BK); SB0;
      loadB(breg, (t + 1) * BK); SB0;
    }
    __builtin_amdgcn_s_setprio(1);
    #pragma unroll
    for (int kk = 0; kk < 2; ++kk) {
      int kByte = kk * 64 + ((lane >> 4) << 4);
      bh8 a[4], b[NF];
      #pragma unroll
      for (int m = 0; m < 4; ++m) {
        int r = wr * 64 + m * 16 + (lane & 15);
        a[m] = *(const bh8*)(lds + r * 128 + (kByte ^ ((r & 7) << 4)));
      }
      #pragma unroll
      for (int n = 0; n < NF; ++n) {
        int r = wc * 128 + n * 16 + (lane & 15);
        b[n] = *(const bh8*)(Bs + r * 128 + (kByte ^ ((r & 7) << 4)));
      }
      #pragma unroll
      for (int m = 0; m < 4; ++m)
        #pragma unroll
        for (int n = 0; n < NF; ++n)
          acc[m][n] = __builtin_amdgcn_mfma_f32_16x16x32_bf16(a[m], b[n], acc[m][n], 0, 0, 0);
    }
    __builtin_amdgcn_s_setprio(0);
    __builtin_amdgcn_s_barrier(); SB0;       // all waves done reading As/Bs
    if (t + 1 < NT) {
      asm volatile("s_waitcnt vmcnt(8)" ::: "memory"); SB0;  // A(t+1) regs ready
      writeA(areg);                           // overlaps B's remaining latency
      asm volatile("s_waitcnt vmcnt(0)" ::: "memory"); SB0;  // B(t+1) regs ready
      writeB(breg);
      asm volatile("s_waitcnt lgkmcnt(0)" ::: "memory"); SB0;
      __builtin_amdgcn_s_barrier(); SB0;     // tile t+1 published
    }
  }

  // ---- epilogue: GELU + store (C layout m89) ----
  #pragma unroll
  for (int m = 0; m < 4; ++m) {
    #pragma unroll
    for (int n = 0; n < NF; ++n) {
      int rowb = wr * 64 + m * 16 + ((lane >> 4) << 2);
      int col  = n0 + wc * 128 + n * 16 + (lane & 15);
      #pragma unroll
      for (int jj = 0; jj < 4; ++jj) {
        float xv = acc[m][n][jj];
        float y = fminf(fmaxf(xv, -8.f), 8.f);
        float u = 0.7978845608f * (y + 0.044715f * y * y * y);
        float t2 = __expf(-2.f * u);
        float g = __fdividef(y, 1.f + t2);
        actout[(size_t)(row0 + rowb + jj) * N + col] = f2bf(g);
      }
    }
  }
}

// GEMM2, BN=128: grid 512 blocks, LDS 80 KB (dbuf As + Bs-128) -> 2 blocks/CU
// resident (was 1 at 96 KB/256 blocks). Per-XCD co-resident blocks now span
// ONE expert -> 1 MB act panel L2-resident. B: 4 x NT dwordx4 per thread;
// counted vmcnt 4/8/4 mirrors the proven ladder.
template<int K, int N>
__global__ __launch_bounds__(512, 2)
void moe_gemm2(const u16* __restrict__ Abf, const float* __restrict__ Bf,
               u16* __restrict__ outp)
{
  constexpr int BM = 256, BN = 128, BK = 64;
  constexpr int NB = N / BN;                  // 8
  constexpr int NT = K / BK;                  // 32
  constexpr int NF = BN / 32;                 // 4
  constexpr int ABYTES = BM * 128;            // 32 KB
  __shared__ __align__(16) char lds[2 * ABYTES + BN * 128];  // 80 KB
  char* Bs = lds + 2 * ABYTES;

  const int d = blockIdx.y * NB + blockIdx.x;
  const int x = d & 7, j = d >> 3;
  const int e  = x * (NE / 8) + j / NB;
  const int n0 = (j % NB) * BN;
  const int row0 = e * PER_E;
  const int tid  = threadIdx.x;
  const int lane = tid & 63, wid = tid >> 6;
  const int wr   = wid >> 1, wc = wid & 1;    // 4x2 waves: 64 x 64 each

  const u16*   Arow = Abf + (size_t)row0 * K;
  const float* Bsrc = Bf + (size_t)e * K * N + n0;
  const int nq = (tid & 31) * 4;              // B: n-quad base (128 cols)
  const int kg = tid >> 5;                    // B: k-quad group (0..15, 4 rows each)

  auto stageA = [&](int buf, int k0) {
    char* dst = lds + buf * ABYTES;
    #pragma unroll
    for (int i = 0; i < 4; ++i) {
      int c = i * 512 + tid;
      int r = c >> 3, kc = c & 7;
      int kswz = kc ^ (r & 7);
      __builtin_amdgcn_global_load_lds(
          (const void*)(Arow + (size_t)r * K + k0 + kswz * 8),
          (void*)(dst + c * 16), 16, 0, 0);
    }
  };
  // B: 4 x NT dwordx4; br4[jj] = B[k0+kg*4+jj][nq..nq+3]
  auto loadB = [&](f4* br4, int k0) {
    #pragma unroll
    for (int jj = 0; jj < 4; ++jj)
      br4[jj] = __builtin_nontemporal_load(
          (const f4*)(Bsrc + (size_t)(k0 + kg * 4 + jj) * N + nq));
  };
  // per n in quad: 4 k-values -> 2 u32 (k-adjacent pairs) -> ds_write_b64 at
  // chunk (kg>>1) XOR swizzle + half-chunk (kg&1)*8
  auto writeB = [&](const f4* br4) {
    #pragma unroll
    for (int i = 0; i < 4; ++i) {
      int n = nq + i;
      u32x2 q;
      q[0] = pk2(br4[0][i], br4[1][i]);
      q[1] = pk2(br4[2][i], br4[3][i]);
      *(u32x2*)(Bs + n * 128 + (((kg >> 1) * 16) ^ ((n & 7) << 4)) + (kg & 1) * 8) = q;
    }
  };

  f4 acc[4][NF] = {};
  f4 breg[4];

  loadB(breg, 0); SB0;
  stageA(0, 0);
  asm volatile("s_waitcnt vmcnt(4)" ::: "memory"); SB0;   // B(0) ready; A(0) flies
  writeB(breg);
  asm volatile("s_waitcnt lgkmcnt(0)" ::: "memory"); SB0;
  __builtin_amdgcn_s_barrier(); SB0;

  int cur = 0;
  for (int t = 0; t < NT; ++t) {
    const char* As = lds + cur * ABYTES;
    if (t + 1 < NT) {
      loadB(breg, (t + 1) * BK); SB0;
      stageA(cur ^ 1, (t + 1) * BK);
      asm volatile("s_waitcnt vmcnt(8)" ::: "memory");    // A(t) landed; 8 fly
    } else {
      asm volatile("s_waitcnt vmcnt(0)" ::: "memory");
    }
    SB0;
    __builtin_amdgcn_s_setprio(1);
    #pragma unroll
    for (int kk = 0; kk < 2; ++kk) {
      int kByte = kk * 64 + ((lane >> 4) << 4);
      bh8 a[4], b[NF];
      #pragma unroll
      for (int m = 0; m < 4; ++m) {
        int r = wr * 64 + m * 16 + (lane & 15);
        a[m] = *(const bh8*)(As + r * 128 + (kByte ^ ((r & 7) << 4)));
      }
      #pragma unroll
      for (int n = 0; n < NF; ++n) {
        int r = wc * 64 + n * 16 + (lane & 15);
        b[n] = *(const bh8*)(Bs + r * 128 + (kByte ^ ((r & 7) << 4)));
      }
      #pragma unroll
      for (int m = 0; m < 4; ++m)
        #pragma unroll
        for (int n = 0; n < NF; ++n)
          acc[m][n] = __builtin_amdgcn_mfma_f32_16x16x32_bf16(a[m], b[n], acc[m][n], 0, 0, 0);
    }
    __builtin_amdgcn_s_setprio(0);
    __builtin_amdgcn_s_barrier(); SB0;
    if (t + 1 < NT) {
      asm volatile("s_waitcnt vmcnt(4)" ::: "memory"); SB0;  // B(t+1) ready; A(t+1) flies
      writeB(breg);
      asm volatile("s_waitcnt lgkmcnt(0)" ::: "memory"); SB0;
      __builtin_amdgcn_s_barrier(); SB0;
      cur ^= 1;
    }
  }

  #pragma unroll
  for (int m = 0; m < 4; ++m) {
    #pragma unroll
    for (int n = 0; n < NF; ++n) {
      int rowb = wr * 64 + m * 16 + ((lane >> 4) << 2);
      int col  = n0 + wc * 64 + n * 16 + (lane & 15);
      #pragma unroll
      for (int jj = 0; jj < 4; ++jj)
        outp[(size_t)(row0 + rowb + jj) * N + col] = f2bf(acc[m][n][jj]);
    }
  }
}

// out[t][:] = h2[sidx[2t]][:] + h2[sidx[2t+1]][:]  (NT in, NT out)
__global__ void k_reduce(const u16* __restrict__ h2, const int* __restrict__ sidx,
                         float* __restrict__ out) {
  for (int i = blockIdx.x * 256 + threadIdx.x; i < NTOK * (HD / 4);
       i += 2048 * 256) {
    int t = i >> 8, c = i & 255;
    const u16* r0 = h2 + (size_t)sidx[2 * t] * HD + c * 4;
    const u16* r1 = h2 + (size_t)sidx[2 * t + 1] * HD + c * 4;
    u32x2 v0 = __builtin_nontemporal_load((const u32x2*)r0);
    u32x2 v1 = __builtin_nontemporal_load((const u32x2*)r1);
    u16 a0[4], a1[4];
    *(u32x2*)a0 = v0;
    *(u32x2*)a1 = v1;
    f4 s;
    #pragma unroll
    for (int jj = 0; jj < 4; ++jj) s[jj] = bf2f(a0[jj]) + bf2f(a1[jj]);
    __builtin_nontemporal_store(s, (f4*)(out + (size_t)t * HD + c * 4));
  }
}

extern "C" void kernel_launch(void* const* d_in, const int* in_sizes, int n_in,
                              void* d_out, int out_size, void* d_ws, size_t ws_size,
                              hipStream_t stream) {
  const float* inp  = (const float*)d_in[0];
  const float* w1   = (const float*)d_in[1];
  const float* w2   = (const float*)d_in[2];
  const int*   sidx = (const int*)d_in[3];
  float* out = (float*)d_out;

  char* ws   = (char*)d_ws;
  int*   s2t = (int*)ws;                                          // 64 KB
  u16*   act = (u16*)(ws + (1 << 20) + (32u << 20));              // 64 MB bf16 [MTOT][FFND]
  u16*   h2  = (u16*)(ws + (1 << 20) + (96u << 20));              // 32 MB bf16 [MTOT][HD]

  k_build_s2t<<<MTOT / 256, 256, 0, stream>>>(sidx, s2t);
  moe_gemm1<HD, FFND><<<dim3(FFND / 256, NE), 512, 0, stream>>>(inp, s2t, w1, act);
  moe_gemm2<FFND, HD><<<dim3(HD / 128, NE), 512, 0, stream>>>(act, w2, h2);
  k_reduce<<<2048, 256, 0, stream>>>(h2, sidx, out);
}

// Round 22
// 262.154 us; speedup vs baseline: 1.0859x; 1.0859x over previous
//
#include <hip/hip_runtime.h>
#include <hip/hip_bf16.h>
#include <math.h>

#define NTOK 8192
#define HD   1024
#define FFND 2048
#define NE   64
#define MTOT 16384   // NTOK * TOPK
#define PER_E 256    // MTOT / NE

typedef __attribute__((ext_vector_type(8))) short bh8;
typedef __attribute__((ext_vector_type(4))) float f4;
typedef __attribute__((ext_vector_type(2))) unsigned int u32x2;
typedef __attribute__((ext_vector_type(4))) unsigned int u32x4;
typedef unsigned short u16;
typedef unsigned int   u32;

#define SB0 __builtin_amdgcn_sched_barrier(0)

__device__ __forceinline__ u16 f2bf(float f) {
  union { float f; u32 u; } x; x.f = f;
  u32 r = x.u + 0x7fffu + ((x.u >> 16) & 1u);   // round-nearest-even
  return (u16)(r >> 16);
}

__device__ __forceinline__ float bf2f(u16 b) {
  union { u32 u; float f; } x; x.u = ((u32)b) << 16; return x.f;
}

__device__ __forceinline__ u32 pk2(float lo, float hi) {
  __hip_bfloat162 h = __float22bfloat162_rn(make_float2(lo, hi));
  union { __hip_bfloat162 h; u32 u; } c; c.h = h;
  return c.u;
}

// slot -> source token map. scatter_index flat: sidx[t*2+k] = slot.
__global__ void k_build_s2t(const int* __restrict__ sidx, int* __restrict__ s2t) {
  int i = blockIdx.x * 256 + threadIdx.x;   // i in [0, MTOT)
  s2t[sidx[i]] = i >> 1;
}

// GEMM1 with FUSED gather (round-20 proven): A rows straight from inp[s2t[row]]
// (f32), reg-staged + cvt_pk -> As (XOR-preswizzled). Split counted drain.
template<int K, int N>
__global__ __launch_bounds__(512, 2)
void moe_gemm1(const float* __restrict__ inp, const int* __restrict__ s2t,
               const float* __restrict__ Bf, u16* __restrict__ actout)
{
  constexpr int BM = 256, BN = 256, BK = 64;
  constexpr int NB = N / BN;
  constexpr int NT = K / BK;
  constexpr int NF = 8;
  constexpr int ABYTES = BM * 128;            // 32 KB
  __shared__ __align__(16) char lds[ABYTES + BN * 128];  // 64 KB
  char* Bs = lds + ABYTES;

  const int d = blockIdx.y * NB + blockIdx.x;
  const int x = d & 7, j = d >> 3;
  const int e  = x * (NE / 8) + j / NB;
  const int n0 = (j % NB) * BN;
  const int row0 = e * PER_E;
  const int tid  = threadIdx.x;
  const int lane = tid & 63, wid = tid >> 6;
  const int wr   = wid >> 1, wc = wid & 1;    // 4x2 waves: 64 x 128 each

  const float* Bsrc = Bf + (size_t)e * K * N + n0;
  const int nq = (tid & 63) * 4;              // B: n-quad base
  const int kg = tid >> 6;                    // B: k-octet group

  // my 4 A-rows and their source tokens
  int arow[4]; const float* asrc[4];
  #pragma unroll
  for (int i = 0; i < 4; ++i) {
    int c = i * 512 + tid;
    arow[i] = c >> 3;
    asrc[i] = inp + (size_t)s2t[row0 + arow[i]] * K;
  }

  auto loadA = [&](f4* ar, int k0) {
    #pragma unroll
    for (int i = 0; i < 4; ++i) {
      int c = i * 512 + tid;
      int kc = c & 7, r = arow[i];
      int kswz = kc ^ (r & 7);
      const float* p = asrc[i] + k0 + kswz * 8;
      ar[i * 2]     = *(const f4*)(p);
      ar[i * 2 + 1] = *(const f4*)(p + 4);
    }
  };
  auto writeA = [&](const f4* ar) {
    #pragma unroll
    for (int i = 0; i < 4; ++i) {
      int c = i * 512 + tid;
      u32 q[4];
      q[0] = pk2(ar[i * 2][0],     ar[i * 2][1]);
      q[1] = pk2(ar[i * 2][2],     ar[i * 2][3]);
      q[2] = pk2(ar[i * 2 + 1][0], ar[i * 2 + 1][1]);
      q[3] = pk2(ar[i * 2 + 1][2], ar[i * 2 + 1][3]);
      *(uint4*)(lds + c * 16) = *(uint4*)q;   // linear dest, src pre-swizzled
    }
  };
  auto loadB = [&](f4* br4, int k0) {
    #pragma unroll
    for (int jj = 0; jj < 8; ++jj)
      br4[jj] = __builtin_nontemporal_load(
          (const f4*)(Bsrc + (size_t)(k0 + kg * 8 + jj) * N + nq));
  };
  auto writeB = [&](const f4* br4) {
    #pragma unroll
    for (int i = 0; i < 4; ++i) {
      int n = nq + i;
      u32 q[4];
      #pragma unroll
      for (int jj = 0; jj < 4; ++jj)
        q[jj] = pk2(br4[2 * jj][i], br4[2 * jj + 1][i]);
      *(uint4*)(Bs + n * 128 + ((kg * 16) ^ ((n & 7) << 4))) = *(uint4*)q;
    }
  };

  f4 acc[4][NF] = {};
  f4 breg[8], areg[8];

  // ---- prologue: tile 0 (A older, B newer) ----
  loadA(areg, 0); SB0;
  loadB(breg, 0); SB0;
  asm volatile("s_waitcnt vmcnt(8)" ::: "memory"); SB0;   // A ready
  writeA(areg);
  asm volatile("s_waitcnt vmcnt(0)" ::: "memory"); SB0;   // B ready
  writeB(breg);
  asm volatile("s_waitcnt lgkmcnt(0)" ::: "memory"); SB0;
  __builtin_amdgcn_s_barrier(); SB0;

  for (int t = 0; t < NT; ++t) {
    if (t + 1 < NT) {
      loadA(areg, (t + 1) * BK); SB0;
      loadB(breg, (t + 1) * BK); SB0;
    }
    __builtin_amdgcn_s_setprio(1);
    #pragma unroll
    for (int kk = 0; kk < 2; ++kk) {
      int kByte = kk * 64 + ((lane >> 4) << 4);
      bh8 a[4], b[NF];
      #pragma unroll
      for (int m = 0; m < 4; ++m) {
        int r = wr * 64 + m * 16 + (lane & 15);
        a[m] = *(const bh8*)(lds + r * 128 + (kByte ^ ((r & 7) << 4)));
      }
      #pragma unroll
      for (int n = 0; n < NF; ++n) {
        int r = wc * 128 + n * 16 + (lane & 15);
        b[n] = *(const bh8*)(Bs + r * 128 + (kByte ^ ((r & 7) << 4)));
      }
      #pragma unroll
      for (int m = 0; m < 4; ++m)
        #pragma unroll
        for (int n = 0; n < NF; ++n)
          acc[m][n] = __builtin_amdgcn_mfma_f32_16x16x32_bf16(a[m], b[n], acc[m][n], 0, 0, 0);
    }
    __builtin_amdgcn_s_setprio(0);
    __builtin_amdgcn_s_barrier(); SB0;       // all waves done reading As/Bs
    if (t + 1 < NT) {
      asm volatile("s_waitcnt vmcnt(8)" ::: "memory"); SB0;  // A(t+1) regs ready
      writeA(areg);                           // overlaps B's remaining latency
      asm volatile("s_waitcnt vmcnt(0)" ::: "memory"); SB0;  // B(t+1) regs ready
      writeB(breg);
      asm volatile("s_waitcnt lgkmcnt(0)" ::: "memory"); SB0;
      __builtin_amdgcn_s_barrier(); SB0;     // tile t+1 published
    }
  }

  // ---- epilogue: GELU + store (C layout m89) ----
  #pragma unroll
  for (int m = 0; m < 4; ++m) {
    #pragma unroll
    for (int n = 0; n < NF; ++n) {
      int rowb = wr * 64 + m * 16 + ((lane >> 4) << 2);
      int col  = n0 + wc * 128 + n * 16 + (lane & 15);
      #pragma unroll
      for (int jj = 0; jj < 4; ++jj) {
        float xv = acc[m][n][jj];
        float y = fminf(fmaxf(xv, -8.f), 8.f);
        float u = 0.7978845608f * (y + 0.044715f * y * y * y);
        float t2 = __expf(-2.f * u);
        float g = __fdividef(y, 1.f + t2);
        actout[(size_t)(row0 + rowb + jj) * N + col] = f2bf(g);
      }
    }
  }
}

// GEMM2, BN=256, structurally mirrors GEMM1's proven form: reg-staged A
// (bf16 uint4 loads, no conversion), single-buffered As+Bs = 64 KB, split
// counted drain (vmcnt(8) -> writeA overlaps B tail; vmcnt(0) -> writeB).
template<int K, int N>
__global__ __launch_bounds__(512, 2)
void moe_gemm2(const u16* __restrict__ Abf, const float* __restrict__ Bf,
               u16* __restrict__ outp)
{
  constexpr int BM = 256, BN = 256, BK = 64;
  constexpr int NB = N / BN;
  constexpr int NT = K / BK;
  constexpr int NF = 8;
  constexpr int ABYTES = BM * 128;            // 32 KB
  __shared__ __align__(16) char lds[ABYTES + BN * 128];  // 64 KB
  char* Bs = lds + ABYTES;

  const int d = blockIdx.y * NB + blockIdx.x;
  const int x = d & 7, j = d >> 3;
  const int e  = x * (NE / 8) + j / NB;
  const int n0 = (j % NB) * BN;
  const int row0 = e * PER_E;
  const int tid  = threadIdx.x;
  const int lane = tid & 63, wid = tid >> 6;
  const int wr   = wid >> 1, wc = wid & 1;    // 4x2 waves: 64 x 128 each

  const u16*   Arow = Abf + (size_t)row0 * K;
  const float* Bsrc = Bf + (size_t)e * K * N + n0;
  const int nq = (tid & 63) * 4;
  const int kg = tid >> 6;

  // A: 4 x uint4 per thread (bf16, no conversion), src pre-swizzled
  auto loadA = [&](u32x4* ar, int k0) {
    #pragma unroll
    for (int i = 0; i < 4; ++i) {
      int c = i * 512 + tid;
      int r = c >> 3, kc = c & 7;
      int kswz = kc ^ (r & 7);
      ar[i] = *(const u32x4*)(Arow + (size_t)r * K + k0 + kswz * 8);
    }
  };
  auto writeA = [&](const u32x4* ar) {
    #pragma unroll
    for (int i = 0; i < 4; ++i) {
      int c = i * 512 + tid;
      *(u32x4*)(lds + c * 16) = ar[i];        // linear dest, src pre-swizzled
    }
  };
  auto loadB = [&](f4* br4, int k0) {
    #pragma unroll
    for (int jj = 0; jj < 8; ++jj)
      br4[jj] = __builtin_nontemporal_load(
          (const f4*)(Bsrc + (size_t)(k0 + kg * 8 + jj) * N + nq));
  };
  auto writeB = [&](const f4* br4) {
    #pragma unroll
    for (int i = 0; i < 4; ++i) {
      int n = nq + i;
      u32 q[4];
      #pragma unroll
      for (int jj = 0; jj < 4; ++jj)
        q[jj] = pk2(br4[2 * jj][i], br4[2 * jj + 1][i]);
      *(uint4*)(Bs + n * 128 + ((kg * 16) ^ ((n & 7) << 4))) = *(uint4*)q;
    }
  };

  f4 acc[4][NF] = {};
  f4 breg[8];
  u32x4 areg[4];

  // ---- prologue: tile 0 (A older, B newer) ----
  loadA(areg, 0); SB0;
  loadB(breg, 0); SB0;
  asm volatile("s_waitcnt vmcnt(8)" ::: "memory"); SB0;   // A ready
  writeA(areg);
  asm volatile("s_waitcnt vmcnt(0)" ::: "memory"); SB0;   // B ready
  writeB(breg);
  asm volatile("s_waitcnt lgkmcnt(0)" ::: "memory"); SB0;
  __builtin_amdgcn_s_barrier(); SB0;

  for (int t = 0; t < NT; ++t) {
    if (t + 1 < NT) {
      loadA(areg, (t + 1) * BK); SB0;
      loadB(breg, (t + 1) * BK); SB0;
    }
    __builtin_amdgcn_s_setprio(1);
    #pragma unroll
    for (int kk = 0; kk < 2; ++kk) {
      int kByte = kk * 64 + ((lane >> 4) << 4);
      bh8 a[4], b[NF];
      #pragma unroll
      for (int m = 0; m < 4; ++m) {
        int r = wr * 64 + m * 16 + (lane & 15);
        a[m] = *(const bh8*)(lds + r * 128 + (kByte ^ ((r & 7) << 4)));
      }
      #pragma unroll
      for (int n = 0; n < NF; ++n) {
        int r = wc * 128 + n * 16 + (lane & 15);
        b[n] = *(const bh8*)(Bs + r * 128 + (kByte ^ ((r & 7) << 4)));
      }
      #pragma unroll
      for (int m = 0; m < 4; ++m)
        #pragma unroll
        for (int n = 0; n < NF; ++n)
          acc[m][n] = __builtin_amdgcn_mfma_f32_16x16x32_bf16(a[m], b[n], acc[m][n], 0, 0, 0);
    }
    __builtin_amdgcn_s_setprio(0);
    __builtin_amdgcn_s_barrier(); SB0;       // all waves done reading As/Bs
    if (t + 1 < NT) {
      asm volatile("s_waitcnt vmcnt(8)" ::: "memory"); SB0;  // A(t+1) regs ready
      writeA(areg);                           // overlaps B's remaining latency
      asm volatile("s_waitcnt vmcnt(0)" ::: "memory"); SB0;  // B(t+1) regs ready
      writeB(breg);
      asm volatile("s_waitcnt lgkmcnt(0)" ::: "memory"); SB0;
      __builtin_amdgcn_s_barrier(); SB0;     // tile t+1 published
    }
  }

  #pragma unroll
  for (int m = 0; m < 4; ++m) {
    #pragma unroll
    for (int n = 0; n < NF; ++n) {
      int rowb = wr * 64 + m * 16 + ((lane >> 4) << 2);
      int col  = n0 + wc * 128 + n * 16 + (lane & 15);
      #pragma unroll
      for (int jj = 0; jj < 4; ++jj)
        outp[(size_t)(row0 + rowb + jj) * N + col] = f2bf(acc[m][n][jj]);
    }
  }
}

// out[t][:] = h2[sidx[2t]][:] + h2[sidx[2t+1]][:]  (NT in, NT out)
__global__ void k_reduce(const u16* __restrict__ h2, const int* __restrict__ sidx,
                         float* __restrict__ out) {
  for (int i = blockIdx.x * 256 + threadIdx.x; i < NTOK * (HD / 4);
       i += 2048 * 256) {
    int t = i >> 8, c = i & 255;
    const u16* r0 = h2 + (size_t)sidx[2 * t] * HD + c * 4;
    const u16* r1 = h2 + (size_t)sidx[2 * t + 1] * HD + c * 4;
    u32x2 v0 = __builtin_nontemporal_load((const u32x2*)r0);
    u32x2 v1 = __builtin_nontemporal_load((const u32x2*)r1);
    u16 a0[4], a1[4];
    *(u32x2*)a0 = v0;
    *(u32x2*)a1 = v1;
    f4 s;
    #pragma unroll
    for (int jj = 0; jj < 4; ++jj) s[jj] = bf2f(a0[jj]) + bf2f(a1[jj]);
    __builtin_nontemporal_store(s, (f4*)(out + (size_t)t * HD + c * 4));
  }
}

extern "C" void kernel_launch(void* const* d_in, const int* in_sizes, int n_in,
                              void* d_out, int out_size, void* d_ws, size_t ws_size,
                              hipStream_t stream) {
  const float* inp  = (const float*)d_in[0];
  const float* w1   = (const float*)d_in[1];
  const float* w2   = (const float*)d_in[2];
  const int*   sidx = (const int*)d_in[3];
  float* out = (float*)d_out;

  char* ws   = (char*)d_ws;
  int*   s2t = (int*)ws;                                          // 64 KB
  u16*   act = (u16*)(ws + (1 << 20) + (32u << 20));              // 64 MB bf16 [MTOT][FFND]
  u16*   h2  = (u16*)(ws + (1 << 20) + (96u << 20));              // 32 MB bf16 [MTOT][HD]

  k_build_s2t<<<MTOT / 256, 256, 0, stream>>>(sidx, s2t);
  moe_gemm1<HD, FFND><<<dim3(FFND / 256, NE), 512, 0, stream>>>(inp, s2t, w1, act);
  moe_gemm2<FFND, HD><<<dim3(HD / 256, NE), 512, 0, stream>>>(act, w2, h2);
  k_reduce<<<2048, 256, 0, stream>>>(h2, sidx, out);
}